// Round 2
// baseline (182.939 us; speedup 1.0000x reference)
//
#include <hip/hip_runtime.h>
#include <math.h>

// Problem constants (fixed by the reference):
constexpr int B = 4, C = 64, N = 65536, K = 16;

// ---------------------------------------------------------------------------
// Kernel 1: transpose features [B, C, N] -> ft [B, N, C]
// 64x64 tiles through padded LDS; coalesced 256B reads and writes.
// ---------------------------------------------------------------------------
__global__ __launch_bounds__(256) void transpose_kernel(
    const float* __restrict__ f, float* __restrict__ ft) {
  __shared__ float tile[64][65];
  const int n0 = blockIdx.x * 64;
  const int b  = blockIdx.y;
  const float* fb  = f  + (size_t)b * C * N;
  float*       ftb = ft + (size_t)b * N * C;
  const int tx = threadIdx.x;  // 0..63
  const int ty = threadIdx.y;  // 0..3

#pragma unroll
  for (int i = 0; i < 64; i += 4) {
    const int c = ty + i;
    tile[c][tx] = fb[(size_t)c * N + n0 + tx];  // coalesced along n
  }
  __syncthreads();
#pragma unroll
  for (int i = 0; i < 64; i += 4) {
    const int n = ty + i;
    ftb[(size_t)(n0 + n) * C + tx] = tile[tx][n];  // coalesced along c
  }
}

// ---------------------------------------------------------------------------
// Kernel 2: gather-max v2.
// Block = 256 threads = 4 waves; block covers 256 n, each wave owns 64 n.
// float4 gather: lane (g = lane>>4, c4 = lane&15) loads ft[idx(n=g)][c4*4..+3]
// -> one wave instruction = 4 rows x 256B = 1 KiB, fully coalesced.
// Per-wave private 16x68 chunk tile in LDS for the n<->c transpose; no
// __syncthreads needed anywhere (all LDS traffic is wave-private slices).
// ---------------------------------------------------------------------------
__global__ __launch_bounds__(256, 4) void gather_max_v2(
    const float* __restrict__ ft, const int* __restrict__ nb,
    float* __restrict__ out) {
  __shared__ int   idx_s[K][256];
  __shared__ float tile[4][16][68];  // per-wave [n-chunk 16][c 64 + pad 4]

  const int t    = threadIdx.x;
  const int wave = t >> 6;
  const int lane = t & 63;
  const int g    = lane >> 4;  // 0..3 : n within 4-n group
  const int c4   = lane & 15;  // float4 column index (c = 4*c4 .. 4*c4+3)
  const int n0   = blockIdx.x * 256;
  const int b    = blockIdx.y;

  const float* ftb  = ft  + (size_t)b * N * C;
  const int*   nbb  = nb  + (size_t)b * K * N;
  float*       outb = out + (size_t)b * C * N;

  // Stage indices: 16 coalesced 1 KiB loads. Each wave writes (and later
  // reads) only columns [wave*64, wave*64+64) -> wave-synchronous, no barrier.
#pragma unroll
  for (int k = 0; k < K; ++k) {
    idx_s[k][t] = nbb[(size_t)k * N + n0 + t];
  }

  const int wbase = wave * 64;

  for (int chunk = 0; chunk < 4; ++chunk) {  // 16 n per chunk
    for (int it = 0; it < 4; ++it) {         // 4 n per iteration
      const int n_loc = chunk * 16 + it * 4 + g;
      float4 acc = make_float4(-INFINITY, -INFINITY, -INFINITY, -INFINITY);
#pragma unroll
      for (int k = 0; k < K; ++k) {
        const int idx = idx_s[k][wbase + n_loc];
        const float4 v = *reinterpret_cast<const float4*>(
            ftb + ((size_t)idx << 6) + (c4 << 2));
        acc.x = fmaxf(acc.x, v.x);
        acc.y = fmaxf(acc.y, v.y);
        acc.z = fmaxf(acc.z, v.z);
        acc.w = fmaxf(acc.w, v.w);
      }
      // tile write: banks (4*(it*4+g) + 4*c4) mod 32 -- spread by +68 pad
      *reinterpret_cast<float4*>(&tile[wave][it * 4 + g][c4 << 2]) = acc;
    }
    // Wave-private LDS round-trip: LDS pipe is in-order per wave; fence the
    // compiler so it can't reorder the reads above the writes.
    asm volatile("s_waitcnt lgkmcnt(0)" ::: "memory");

    // Transposed store: 16 n x 64 c chunk. lane -> (n_off, c_sub);
    // each instruction stores 4 contiguous 64B segments (one per c_sub).
    const int n_off = lane & 15;
    const int c_sub = lane >> 4;
    const int n_glob = n0 + wbase + chunk * 16 + n_off;
#pragma unroll
    for (int ci = 0; ci < 16; ++ci) {
      const int c = ci * 4 + c_sub;
      // LDS read banks: (4*n_off + c_sub + 4*ci) mod 32 -> exact 2-way, free
      outb[(size_t)c * N + n_glob] = tile[wave][n_off][c];
    }
    asm volatile("" ::: "memory");  // keep next chunk's writes below the reads
  }
}

// ---------------------------------------------------------------------------
// Fallback (workspace too small): direct gather, correct but slow.
// ---------------------------------------------------------------------------
__global__ __launch_bounds__(256) void naive_kernel(
    const float* __restrict__ f, const int* __restrict__ nb,
    float* __restrict__ out) {
  const int n = blockIdx.x * 256 + threadIdx.x;
  const int c = blockIdx.y;
  const int b = blockIdx.z;
  if (n >= N) return;
  const float* fb  = f  + (size_t)b * C * N + (size_t)c * N;
  const int*   nbb = nb + (size_t)b * K * N;
  float acc = -INFINITY;
#pragma unroll
  for (int k = 0; k < K; ++k) {
    acc = fmaxf(acc, fb[nbb[(size_t)k * N + n]]);
  }
  out[(size_t)b * C * N + (size_t)c * N + n] = acc;
}

extern "C" void kernel_launch(void* const* d_in, const int* in_sizes, int n_in,
                              void* d_out, int out_size, void* d_ws, size_t ws_size,
                              hipStream_t stream) {
  const float* f   = (const float*)d_in[0];
  const int*   nb  = (const int*)d_in[1];
  float*       out = (float*)d_out;

  const size_t need = (size_t)B * N * C * sizeof(float);
  if (ws_size >= need) {
    float* ft = (float*)d_ws;
    transpose_kernel<<<dim3(N / 64, B), dim3(64, 4), 0, stream>>>(f, ft);
    gather_max_v2<<<dim3(N / 256, B), 256, 0, stream>>>(ft, nb, out);
  } else {
    naive_kernel<<<dim3((N + 255) / 256, C, B), 256, 0, stream>>>(f, nb, out);
  }
}

// Round 3
// 180.231 us; speedup vs baseline: 1.0150x; 1.0150x over previous
//
#include <hip/hip_runtime.h>
#include <math.h>

// Problem constants (fixed by the reference):
constexpr int B = 4, C = 64, N = 65536, K = 16;

// ---------------------------------------------------------------------------
// Kernel 1: transpose features [B, C, N] -> ft [B, N, C]
// 64x64 tiles through padded LDS; coalesced 256B reads and writes.
// ---------------------------------------------------------------------------
__global__ __launch_bounds__(256) void transpose_kernel(
    const float* __restrict__ f, float* __restrict__ ft) {
  __shared__ float tile[64][65];
  const int n0 = blockIdx.x * 64;
  const int b  = blockIdx.y;
  const float* fb  = f  + (size_t)b * C * N;
  float*       ftb = ft + (size_t)b * N * C;
  const int tx = threadIdx.x;  // 0..63
  const int ty = threadIdx.y;  // 0..3

#pragma unroll
  for (int i = 0; i < 64; i += 4) {
    const int c = ty + i;
    tile[c][tx] = fb[(size_t)c * N + n0 + tx];  // coalesced along n
  }
  __syncthreads();
#pragma unroll
  for (int i = 0; i < 64; i += 4) {
    const int n = ty + i;
    ftb[(size_t)(n0 + n) * C + tx] = tile[tx][n];  // coalesced along c
  }
}

// ---------------------------------------------------------------------------
// Kernel 2: gather-max v3 — deep ILP version.
// Same decomposition as v2 (block = 4 waves x 64 n; lane (g,c4) owns
// (n-sub g, channels 4*c4..4*c4+3)), but the k-loop is restructured so all
// 16 gather loads are issued back-to-back into v[16] before any max:
//   - read 16 indices from LDS into registers (compile-time-indexed array)
//   - issue 16 global_load_dwordx4 (16 KiB in flight per wave)
//   - sequential max drain (first fmax runs at vmcnt(15))
// __launch_bounds__(256,4): cap 128 VGPR (est ~110, no spill) — LDS already
// limits occupancy to 4 blocks/CU = 16 waves/CU, so the cap is free.
// ---------------------------------------------------------------------------
__global__ __launch_bounds__(256, 4) void gather_max_v3(
    const float* __restrict__ ft, const int* __restrict__ nb,
    float* __restrict__ out) {
  __shared__ int   idx_s[K][256];
  __shared__ float tile[4][16][68];  // per-wave [n-chunk 16][c 64 + pad 4]

  const int t    = threadIdx.x;
  const int wave = t >> 6;
  const int lane = t & 63;
  const int g    = lane >> 4;  // 0..3 : n within 4-n group
  const int c4   = lane & 15;  // float4 column index (c = 4*c4 .. 4*c4+3)
  const int n0   = blockIdx.x * 256;
  const int b    = blockIdx.y;

  const float* ftb  = ft  + (size_t)b * N * C;
  const int*   nbb  = nb  + (size_t)b * K * N;
  float*       outb = out + (size_t)b * C * N;

  // Stage indices: 16 coalesced 1 KiB loads. Each wave writes (and later
  // reads) only columns [wave*64, wave*64+64) -> wave-synchronous, no barrier.
#pragma unroll
  for (int k = 0; k < K; ++k) {
    idx_s[k][t] = nbb[(size_t)k * N + n0 + t];
  }

  const int wbase = wave * 64;

  for (int chunk = 0; chunk < 4; ++chunk) {  // 16 n per chunk
    for (int it = 0; it < 4; ++it) {         // 4 n per iteration
      const int n_loc = wbase + chunk * 16 + it * 4 + g;

      // 1) all 16 indices -> registers (static indexing, stays in VGPRs)
      int off[K];
#pragma unroll
      for (int k = 0; k < K; ++k) off[k] = idx_s[k][n_loc];

      // 2) all 16 gather loads issued back-to-back (16 KiB in flight)
      float4 v[K];
#pragma unroll
      for (int k = 0; k < K; ++k) {
        v[k] = *reinterpret_cast<const float4*>(
            ftb + ((size_t)off[k] << 6) + (c4 << 2));
      }

      // 3) sequential drain: max k can execute at vmcnt(15-k)
      float4 acc = v[0];
#pragma unroll
      for (int k = 1; k < K; ++k) {
        acc.x = fmaxf(acc.x, v[k].x);
        acc.y = fmaxf(acc.y, v[k].y);
        acc.z = fmaxf(acc.z, v[k].z);
        acc.w = fmaxf(acc.w, v[k].w);
      }

      *reinterpret_cast<float4*>(&tile[wave][it * 4 + g][c4 << 2]) = acc;
    }
    // Wave-private LDS round-trip: LDS pipe is in-order per wave; fence the
    // compiler so it can't reorder the reads above the writes.
    asm volatile("s_waitcnt lgkmcnt(0)" ::: "memory");

    // Transposed store: 16 n x 64 c chunk. lane -> (n_off, c_sub);
    // each instruction stores 4 contiguous 64B segments (one per c_sub).
    const int n_off = lane & 15;
    const int c_sub = lane >> 4;
    const int n_glob = n0 + wbase + chunk * 16 + n_off;
#pragma unroll
    for (int ci = 0; ci < 16; ++ci) {
      const int c = ci * 4 + c_sub;
      // LDS read banks: (4*n_off + c_sub + 4*ci) mod 32 -> exact 2-way, free
      outb[(size_t)c * N + n_glob] = tile[wave][n_off][c];
    }
    asm volatile("" ::: "memory");  // keep next chunk's writes below the reads
  }
}

// ---------------------------------------------------------------------------
// Fallback (workspace too small): direct gather, correct but slow.
// ---------------------------------------------------------------------------
__global__ __launch_bounds__(256) void naive_kernel(
    const float* __restrict__ f, const int* __restrict__ nb,
    float* __restrict__ out) {
  const int n = blockIdx.x * 256 + threadIdx.x;
  const int c = blockIdx.y;
  const int b = blockIdx.z;
  if (n >= N) return;
  const float* fb  = f  + (size_t)b * C * N + (size_t)c * N;
  const int*   nbb = nb + (size_t)b * K * N;
  float acc = -INFINITY;
#pragma unroll
  for (int k = 0; k < K; ++k) {
    acc = fmaxf(acc, fb[nbb[(size_t)k * N + n]]);
  }
  out[(size_t)b * C * N + (size_t)c * N + n] = acc;
}

extern "C" void kernel_launch(void* const* d_in, const int* in_sizes, int n_in,
                              void* d_out, int out_size, void* d_ws, size_t ws_size,
                              hipStream_t stream) {
  const float* f   = (const float*)d_in[0];
  const int*   nb  = (const int*)d_in[1];
  float*       out = (float*)d_out;

  const size_t need = (size_t)B * N * C * sizeof(float);
  if (ws_size >= need) {
    float* ft = (float*)d_ws;
    transpose_kernel<<<dim3(N / 64, B), dim3(64, 4), 0, stream>>>(f, ft);
    gather_max_v3<<<dim3(N / 256, B), 256, 0, stream>>>(ft, nb, out);
  } else {
    naive_kernel<<<dim3((N + 255) / 256, C, B), 256, 0, stream>>>(f, nb, out);
  }
}

// Round 4
// 99.483 us; speedup vs baseline: 1.8389x; 1.8117x over previous
//
#include <hip/hip_runtime.h>
#include <math.h>

// Problem constants (fixed by the reference):
constexpr int B = 4, C = 64, N = 65536, K = 16;

// Round-to-nearest-even fp32 -> bf16 (inputs are finite normals).
__device__ __forceinline__ unsigned short f2bf(float x) {
  unsigned int u = __float_as_uint(x);
  unsigned int r = (u + 0x7FFFu + ((u >> 16) & 1u)) >> 16;
  return (unsigned short)r;
}

// ---------------------------------------------------------------------------
// Kernel 1: transpose + convert: f fp32 [B, C, N] -> ft bf16 [B, N, C].
// 64x64 tiles through padded LDS; coalesced reads; ushort2 packed stores.
// ---------------------------------------------------------------------------
__global__ __launch_bounds__(256) void transpose_bf16_kernel(
    const float* __restrict__ f, unsigned short* __restrict__ ft) {
  __shared__ float tile[64][65];
  const int n0 = blockIdx.x * 64;
  const int b  = blockIdx.y;
  const float*    fb  = f  + (size_t)b * C * N;
  unsigned short* ftb = ft + (size_t)b * N * C;
  const int tx = threadIdx.x;  // 0..63
  const int ty = threadIdx.y;  // 0..3
  const int t  = ty * 64 + tx;

#pragma unroll
  for (int i = 0; i < 64; i += 4) {
    const int c = ty + i;
    tile[c][tx] = fb[(size_t)c * N + n0 + tx];  // coalesced along n
  }
  __syncthreads();

  // Store phase: thread t -> (c-pair c2 = t&31, n = (t>>5) + 8*i).
  // LDS read banks (2*c2 + n) mod 32: 2-way per instruction -> free.
  const int c2    = t & 31;
  const int nbase = t >> 5;
#pragma unroll
  for (int i = 0; i < 64; i += 8) {
    const int n  = nbase + i;
    const float lo = tile[2 * c2][n];
    const float hi = tile[2 * c2 + 1][n];
    ushort2 pk;
    pk.x = f2bf(lo);
    pk.y = f2bf(hi);
    *reinterpret_cast<ushort2*>(&ftb[(size_t)(n0 + n) * C + 2 * c2]) = pk;
  }
}

// ---------------------------------------------------------------------------
// Kernel 2: gather-max v4 (bf16 feature rows, 128 B each).
// Block = 4 waves x 64 n. Lane (g = lane>>3, c8 = lane&7) loads
// ft[idx(n=g)][8*c8 .. 8*c8+7] as ushort8 (16 B) -> one wave instruction =
// 8 rows x 128 B = 1 KiB, one 128B line-touch per row (half of fp32).
// Max accumulated in fp32 (bf16->fp32 is a shift). Per-wave private LDS
// chunk tile for the n<->c transpose; no __syncthreads anywhere.
// ---------------------------------------------------------------------------
__global__ __launch_bounds__(256, 4) void gather_max_v4(
    const unsigned short* __restrict__ ft, const int* __restrict__ nb,
    float* __restrict__ out) {
  __shared__ int   idx_s[K][256];
  __shared__ float tile[4][16][68];  // per-wave [n-chunk 16][c 64 + pad 4]

  const int t    = threadIdx.x;
  const int wave = t >> 6;
  const int lane = t & 63;
  const int g    = lane >> 3;  // 0..7 : row within 8-row gather group
  const int c8   = lane & 7;   // channel octet: c = 8*c8 .. 8*c8+7
  const int n0   = blockIdx.x * 256;
  const int b    = blockIdx.y;

  const unsigned short* ftb  = ft  + (size_t)b * N * C;
  const int*            nbb  = nb  + (size_t)b * K * N;
  float*                outb = out + (size_t)b * C * N;

  // Stage indices: 16 coalesced 1 KiB loads; wave-private columns, no barrier.
#pragma unroll
  for (int k = 0; k < K; ++k) {
    idx_s[k][t] = nbb[(size_t)k * N + n0 + t];
  }

  const int wbase = wave * 64;

  for (int chunk = 0; chunk < 4; ++chunk) {  // 16 n per chunk
#pragma unroll
    for (int it = 0; it < 2; ++it) {         // 8 n per gather group
      const int n_loc = wbase + chunk * 16 + it * 8 + g;

      float acc[8];
#pragma unroll
      for (int j = 0; j < 8; ++j) acc[j] = -INFINITY;

#pragma unroll
      for (int kb = 0; kb < 2; ++kb) {  // two 8-deep load batches
        int off[8];
#pragma unroll
        for (int k = 0; k < 8; ++k) off[k] = idx_s[kb * 8 + k][n_loc];

        uint4 v[8];
#pragma unroll
        for (int k = 0; k < 8; ++k) {
          v[k] = *reinterpret_cast<const uint4*>(
              ftb + ((size_t)off[k] << 6) + (c8 << 3));
        }

#pragma unroll
        for (int k = 0; k < 8; ++k) {
          const unsigned int w0 = v[k].x, w1 = v[k].y, w2 = v[k].z, w3 = v[k].w;
          acc[0] = fmaxf(acc[0], __uint_as_float(w0 << 16));
          acc[1] = fmaxf(acc[1], __uint_as_float(w0 & 0xFFFF0000u));
          acc[2] = fmaxf(acc[2], __uint_as_float(w1 << 16));
          acc[3] = fmaxf(acc[3], __uint_as_float(w1 & 0xFFFF0000u));
          acc[4] = fmaxf(acc[4], __uint_as_float(w2 << 16));
          acc[5] = fmaxf(acc[5], __uint_as_float(w2 & 0xFFFF0000u));
          acc[6] = fmaxf(acc[6], __uint_as_float(w3 << 16));
          acc[7] = fmaxf(acc[7], __uint_as_float(w3 & 0xFFFF0000u));
        }
      }

      // tile write: two b128 stores per lane; minor bank aliasing, negligible
      // vs the 16 global gathers per n-group.
      const int r = it * 8 + g;
      float4 a0 = make_float4(acc[0], acc[1], acc[2], acc[3]);
      float4 a1 = make_float4(acc[4], acc[5], acc[6], acc[7]);
      *reinterpret_cast<float4*>(&tile[wave][r][c8 * 8])     = a0;
      *reinterpret_cast<float4*>(&tile[wave][r][c8 * 8 + 4]) = a1;
    }
    // Wave-private LDS round-trip: LDS pipe is in-order per wave; fence the
    // compiler so it can't reorder the reads above the writes.
    asm volatile("s_waitcnt lgkmcnt(0)" ::: "memory");

    // Transposed store: 16 n x 64 c chunk. lane -> (n_off, c_sub);
    // each instruction stores 4 contiguous 64B segments (one per c_sub).
    const int n_off = lane & 15;
    const int c_sub = lane >> 4;
    const int n_glob = n0 + wbase + chunk * 16 + n_off;
#pragma unroll
    for (int ci = 0; ci < 16; ++ci) {
      const int c = ci * 4 + c_sub;
      // LDS read banks: (4*n_off + c_sub + 4*ci) mod 32 -> exact 2-way, free
      outb[(size_t)c * N + n_glob] = tile[wave][n_off][c];
    }
    asm volatile("" ::: "memory");  // keep next chunk's writes below the reads
  }
}

// ---------------------------------------------------------------------------
// Fallback (workspace too small): direct gather, correct but slow.
// ---------------------------------------------------------------------------
__global__ __launch_bounds__(256) void naive_kernel(
    const float* __restrict__ f, const int* __restrict__ nb,
    float* __restrict__ out) {
  const int n = blockIdx.x * 256 + threadIdx.x;
  const int c = blockIdx.y;
  const int b = blockIdx.z;
  if (n >= N) return;
  const float* fb  = f  + (size_t)b * C * N + (size_t)c * N;
  const int*   nbb = nb + (size_t)b * K * N;
  float acc = -INFINITY;
#pragma unroll
  for (int k = 0; k < K; ++k) {
    acc = fmaxf(acc, fb[nbb[(size_t)k * N + n]]);
  }
  out[(size_t)b * C * N + (size_t)c * N + n] = acc;
}

extern "C" void kernel_launch(void* const* d_in, const int* in_sizes, int n_in,
                              void* d_out, int out_size, void* d_ws, size_t ws_size,
                              hipStream_t stream) {
  const float* f   = (const float*)d_in[0];
  const int*   nb  = (const int*)d_in[1];
  float*       out = (float*)d_out;

  const size_t need = (size_t)B * N * C * sizeof(unsigned short);
  if (ws_size >= need) {
    unsigned short* ft = (unsigned short*)d_ws;
    transpose_bf16_kernel<<<dim3(N / 64, B), dim3(64, 4), 0, stream>>>(f, ft);
    gather_max_v4<<<dim3(N / 256, B), 256, 0, stream>>>(ft, nb, out);
  } else {
    naive_kernel<<<dim3((N + 255) / 256, C, B), 256, 0, stream>>>(f, nb, out);
  }
}